// Round 1
// baseline (1098.501 us; speedup 1.0000x reference)
//
#include <hip/hip_runtime.h>
#include <hip/hip_bf16.h>

#define BB 256
#define NN 257
#define NT 256   // tokens per batch (N-1)
#define DD 768
#define KC 8     // K clusters
#define VV 10000
#define ITERS 4

__device__ __forceinline__ float waveReduceSum(float v) {
#pragma unroll
    for (int off = 32; off > 0; off >>= 1)
        v += __shfl_xor(v, off, 64);
    return v;
}

__global__ __launch_bounds__(256) void kmeans_kernel(
    const float* __restrict__ tokens,
    const float* __restrict__ vc,
    const int* __restrict__ topk,
    float* __restrict__ out_assign,   // (B, 256, 8) float
    float* __restrict__ delta)        // (V) float accumulators (pre-zeroed)
{
    __shared__ float cent[16][DD];    // 48 KB, normalized centroids (row = 2k+c)
    __shared__ float tsum[DD];        // 3 KB
    __shared__ unsigned mask[NT];     // 1 KB
    __shared__ float ssq[16];
    __shared__ float invn[16];
    __shared__ int sidx[KC];

    const int b = blockIdx.x;
    const int t = threadIdx.x;
    const int lane = t & 63;
    const int wave = t >> 6;

    if (t < KC) sidx[t] = topk[b * KC + t];
    __syncthreads();

    // ---- gather + L2-normalize 16 initial centroid rows (wave w -> rows 4w..4w+3)
#pragma unroll
    for (int rr = 0; rr < 4; ++rr) {
        int r = wave * 4 + rr;
        int k = r >> 1, c = r & 1;
        const float* src = vc + ((size_t)sidx[k] * 2 + c) * DD;
        float vals[12];
        float ss = 0.f;
#pragma unroll
        for (int j = 0; j < 12; ++j) {
            vals[j] = src[lane + 64 * j];
            ss = fmaf(vals[j], vals[j], ss);
        }
        ss = waveReduceSum(ss);
        float iv = 1.0f / fmaxf(sqrtf(ss), 1e-12f);
#pragma unroll
        for (int j = 0; j < 12; ++j)
            cent[r][lane + 64 * j] = vals[j] * iv;
    }

    // ---- tsum[d] = sum_n tp[n][d]  (thread t -> dims t, t+256, t+512)
    const float* tpb = tokens + ((size_t)b * NN + 1) * DD;
    {
        float s0 = 0.f, s1 = 0.f, s2 = 0.f;
        for (int n = 0; n < NT; ++n) {
            const float* row = tpb + (size_t)n * DD;
            s0 += row[t];
            s1 += row[t + 256];
            s2 += row[t + 512];
        }
        tsum[t] = s0; tsum[t + 256] = s1; tsum[t + 512] = s2;
    }
    __syncthreads();

    for (int it = 0; it < ITERS; ++it) {
        // ================= sim phase: thread t owns token t =================
        float acc[16];
#pragma unroll
        for (int kc = 0; kc < 16; ++kc) acc[kc] = 0.f;
        const float* row = tpb + (size_t)t * DD;
#pragma unroll 2
        for (int j = 0; j < DD; j += 4) {
            float4 a = *(const float4*)(row + j);
#pragma unroll
            for (int kc = 0; kc < 16; ++kc) {
                float4 cv = *(const float4*)&cent[kc][j];   // wave-uniform -> LDS broadcast
                acc[kc] = fmaf(a.w, cv.w, fmaf(a.z, cv.z,
                           fmaf(a.y, cv.y, fmaf(a.x, cv.x, acc[kc]))));
            }
        }
        unsigned m = 0;
#pragma unroll
        for (int k = 0; k < KC; ++k)
            if (acc[2 * k + 1] > acc[2 * k]) m |= (1u << k);   // argmax ties -> 0
        mask[t] = m;
        if (it == ITERS - 1) {
            float4* op = (float4*)(out_assign + ((size_t)b * NT + t) * KC);
            op[0] = make_float4((m & 1) ? 1.f : 0.f, (m & 2) ? 1.f : 0.f,
                                (m & 4) ? 1.f : 0.f, (m & 8) ? 1.f : 0.f);
            op[1] = make_float4((m & 16) ? 1.f : 0.f, (m & 32) ? 1.f : 0.f,
                                (m & 64) ? 1.f : 0.f, (m & 128) ? 1.f : 0.f);
        }
        if (t < 16) ssq[t] = 0.f;
        __syncthreads();   // masks + ssq zero visible; all cent reads done

        // ============ accumulate phase: thread t owns dims t+256*i ============
        float c1[3][KC];
#pragma unroll
        for (int i = 0; i < 3; ++i)
#pragma unroll
            for (int k = 0; k < KC; ++k) c1[i][k] = 0.f;
        for (int n = 0; n < NT; ++n) {
            unsigned mn = mask[n];                    // LDS broadcast
            const float* rn = tpb + (size_t)n * DD;
            float v0 = rn[t], v1 = rn[t + 256], v2 = rn[t + 512];  // coalesced
#pragma unroll
            for (int k = 0; k < KC; ++k) {
                bool on = (mn >> k) & 1;
                c1[0][k] += on ? v0 : 0.f;
                c1[1][k] += on ? v1 : 0.f;
                c1[2][k] += on ? v2 : 0.f;
            }
        }
        // c0 = tsum - c1; partial sums of squares per row
        float c0[3][KC];
        float pss[16];
#pragma unroll
        for (int kc = 0; kc < 16; ++kc) pss[kc] = 0.f;
#pragma unroll
        for (int i = 0; i < 3; ++i) {
            float tv = tsum[t + 256 * i];
#pragma unroll
            for (int k = 0; k < KC; ++k) {
                c0[i][k] = tv - c1[i][k];
                pss[2 * k]     = fmaf(c0[i][k], c0[i][k], pss[2 * k]);
                pss[2 * k + 1] = fmaf(c1[i][k], c1[i][k], pss[2 * k + 1]);
            }
        }
#pragma unroll
        for (int kc = 0; kc < 16; ++kc) {
            pss[kc] = waveReduceSum(pss[kc]);
        }
        if (lane == 0) {
#pragma unroll
            for (int kc = 0; kc < 16; ++kc) atomicAdd(&ssq[kc], pss[kc]);
        }
        __syncthreads();   // ssq complete
        if (t < 16) invn[t] = 1.0f / fmaxf(sqrtf(ssq[t]), 1e-12f);
        __syncthreads();   // invn visible
        // write normalized new centroids
#pragma unroll
        for (int i = 0; i < 3; ++i) {
            int d = t + 256 * i;
#pragma unroll
            for (int k = 0; k < KC; ++k) {
                cent[2 * k][d]     = c0[i][k] * invn[2 * k];
                cent[2 * k + 1][d] = c1[i][k] * invn[2 * k + 1];
            }
        }
        __syncthreads();   // cent ready for next iter / epilogue
    }

    // ---- scatter: vc[idx,0,0] += centroids_final[b,k,0,0] (c0 row, element 0)
    if (t < KC) {
        atomicAdd(delta + sidx[t], cent[2 * t][0]);
    }
}

__global__ __launch_bounds__(256) void vcnorm_kernel(
    const float* __restrict__ vc,
    const float* __restrict__ delta,
    float* __restrict__ out)          // (V, 2, D)
{
    const int t = threadIdx.x;
    const int lane = t & 63;
    const int wave = t >> 6;
    const int r = blockIdx.x * 4 + wave;      // row in [0, 2V)
    if (r >= 2 * VV) return;
    const int v = r >> 1;
    const int c = r & 1;
    const float* src = vc + (size_t)r * DD;
    float4 x[3];
#pragma unroll
    for (int j = 0; j < 3; ++j)
        x[j] = *(const float4*)(src + (lane + 64 * j) * 4);
    if (c == 0 && lane == 0) x[0].x += delta[v];
    float ss = 0.f;
#pragma unroll
    for (int j = 0; j < 3; ++j)
        ss += x[j].x * x[j].x + x[j].y * x[j].y + x[j].z * x[j].z + x[j].w * x[j].w;
    ss = waveReduceSum(ss);
    float iv = 1.0f / fmaxf(sqrtf(ss), 1e-12f);
    float* dst = out + (size_t)r * DD;
#pragma unroll
    for (int j = 0; j < 3; ++j) {
        float4 y = make_float4(x[j].x * iv, x[j].y * iv, x[j].z * iv, x[j].w * iv);
        *(float4*)(dst + (lane + 64 * j) * 4) = y;
    }
}

extern "C" void kernel_launch(void* const* d_in, const int* in_sizes, int n_in,
                              void* d_out, int out_size, void* d_ws, size_t ws_size,
                              hipStream_t stream) {
    const float* tokens = (const float*)d_in[0];
    const float* vc     = (const float*)d_in[1];
    const int*   topk   = (const int*)d_in[2];
    float* out          = (float*)d_out;
    float* assignments  = out;                                   // B*NT*KC floats
    float* vcnew        = out + (size_t)BB * NT * KC;            // V*2*D floats
    float* delta        = (float*)d_ws;                          // V floats

    hipMemsetAsync(delta, 0, VV * sizeof(float), stream);
    hipLaunchKernelGGL(kmeans_kernel, dim3(BB), dim3(256), 0, stream,
                       tokens, vc, topk, assignments, delta);
    hipLaunchKernelGGL(vcnorm_kernel, dim3((2 * VV + 3) / 4), dim3(256), 0, stream,
                       vc, delta, vcnew);
}

// Round 2
// 926.947 us; speedup vs baseline: 1.1851x; 1.1851x over previous
//
#include <hip/hip_runtime.h>
#include <hip/hip_bf16.h>

#define BB 256
#define NN 257
#define NT 256   // tokens per batch (N-1)
#define DD 768
#define KC 8     // K clusters
#define VV 10000
#define ITERS 4

__device__ __forceinline__ float waveReduceSum(float v) {
#pragma unroll
    for (int off = 32; off > 0; off >>= 1)
        v += __shfl_xor(v, off, 64);
    return v;
}

// One block (1024 threads, 16 waves) per batch. All per-value fp summation
// chains are bit-identical to the round-1 kernel (which matched the np ref):
//  - sim: per-row fma chain over j identical; rows merely distributed over 4
//    thread-groups (g = t>>8), tokens over t&255.
//  - tsum: per-dim sequential n-chain identical (1 thread per dim).
//  - c1 accumulate: per-(cluster,dim) sequential n-chain identical; group g
//    owns clusters {2g,2g+1} so each slot has exactly one owner (no atomics).
//  - gather-norm: identical per-row code, one wave per row.
__global__ __launch_bounds__(1024) void kmeans_kernel(
    const float* __restrict__ tokens,
    const float* __restrict__ vc,
    const int* __restrict__ topk,
    float* __restrict__ out_assign,   // (B, 256, 8) float
    float* __restrict__ delta)        // (V) float accumulators (pre-zeroed)
{
    __shared__ float cent[16][DD];          // 48 KB  normalized centroids (row = 2k+c)
    __shared__ float c1buf[KC][DD];         // 24 KB  c1 sums (cluster-major)
    __shared__ float tsum[DD];              // 3 KB
    __shared__ unsigned mask[NT];           // 1 KB   combined 8-bit masks
    __shared__ unsigned char maskp[4][NT];  // 1 KB   per-group 2-bit partials
    __shared__ int sidx[KC];

    const int b = blockIdx.x;
    const int t = threadIdx.x;
    const int lane = t & 63;
    const int wave = t >> 6;

    if (t < KC) sidx[t] = topk[b * KC + t];
    __syncthreads();

    // ---- gather + L2-normalize 16 initial centroid rows: wave r -> row r
    {
        const int r = wave;
        const int k = r >> 1, c = r & 1;
        const float* src = vc + ((size_t)sidx[k] * 2 + c) * DD;
        float vals[12];
        float ss = 0.f;
#pragma unroll
        for (int j = 0; j < 12; ++j) {
            vals[j] = src[lane + 64 * j];
            ss = fmaf(vals[j], vals[j], ss);
        }
        ss = waveReduceSum(ss);
        float iv = 1.0f / fmaxf(sqrtf(ss), 1e-12f);
#pragma unroll
        for (int j = 0; j < 12; ++j)
            cent[r][lane + 64 * j] = vals[j] * iv;
    }

    const float* tpb = tokens + ((size_t)b * NN + 1) * DD;

    // ---- tsum[d] = sum_n tp[n][d]; thread t<768 owns dim t (exact sequential chain)
    if (t < DD) {
        float s = 0.f;
        for (int n = 0; n < NT; ++n)
            s += tpb[(size_t)n * DD + t];
        tsum[t] = s;
    }
    __syncthreads();

    const int tok = t & 255;      // token this thread scores in sim phase
    const int g   = t >> 8;       // group: rows 4g..4g+3 (clusters 2g,2g+1)
    const float* row = tpb + (size_t)tok * DD;

    for (int it = 0; it < ITERS; ++it) {
        // ================= sim phase =================
        float acc[4] = {0.f, 0.f, 0.f, 0.f};
#pragma unroll 2
        for (int j = 0; j < DD; j += 4) {
            float4 a = *(const float4*)(row + j);
#pragma unroll
            for (int rr = 0; rr < 4; ++rr) {
                float4 cv = *(const float4*)&cent[g * 4 + rr][j];  // wave-uniform broadcast
                acc[rr] = fmaf(a.w, cv.w, fmaf(a.z, cv.z,
                           fmaf(a.y, cv.y, fmaf(a.x, cv.x, acc[rr]))));
            }
        }
        unsigned m2 = 0;
        if (acc[1] > acc[0]) m2 |= 1u;   // cluster 2g   (ties -> 0, matches argmax)
        if (acc[3] > acc[2]) m2 |= 2u;   // cluster 2g+1
        maskp[g][tok] = (unsigned char)m2;
        __syncthreads();

        // combine partial masks; emit assignments on last iter
        if (t < NT) {
            unsigned m = (unsigned)maskp[0][t]
                       | ((unsigned)maskp[1][t] << 2)
                       | ((unsigned)maskp[2][t] << 4)
                       | ((unsigned)maskp[3][t] << 6);
            mask[t] = m;
            if (it == ITERS - 1) {
                float4* op = (float4*)(out_assign + ((size_t)b * NT + t) * KC);
                op[0] = make_float4((m & 1) ? 1.f : 0.f, (m & 2) ? 1.f : 0.f,
                                    (m & 4) ? 1.f : 0.f, (m & 8) ? 1.f : 0.f);
                op[1] = make_float4((m & 16) ? 1.f : 0.f, (m & 32) ? 1.f : 0.f,
                                    (m & 64) ? 1.f : 0.f, (m & 128) ? 1.f : 0.f);
            }
        }
        __syncthreads();

        // ============ accumulate phase ============
        // group g -> clusters {2g, 2g+1}; thread tt -> dims tt, tt+256, tt+512
        {
            const int tt = t & 255;
            float c1[3][2] = {{0.f, 0.f}, {0.f, 0.f}, {0.f, 0.f}};
            for (int n = 0; n < NT; ++n) {
                unsigned mn = mask[n];                 // LDS broadcast
                const float* rn = tpb + (size_t)n * DD;
                float v0 = rn[tt], v1 = rn[tt + 256], v2 = rn[tt + 512];  // coalesced, L1-shared
#pragma unroll
                for (int kk = 0; kk < 2; ++kk) {
                    bool on = (mn >> (2 * g + kk)) & 1;
                    c1[0][kk] += on ? v0 : 0.f;
                    c1[1][kk] += on ? v1 : 0.f;
                    c1[2][kk] += on ? v2 : 0.f;
                }
            }
#pragma unroll
            for (int i = 0; i < 3; ++i)
#pragma unroll
                for (int kk = 0; kk < 2; ++kk)
                    c1buf[2 * g + kk][tt + 256 * i] = c1[i][kk];
        }
        __syncthreads();

        // ============ normalize phase: wave r -> row r (= 2k+cc) ============
        {
            const int k = wave >> 1, cc = wave & 1;
            float vals[12];
            float ss = 0.f;
#pragma unroll
            for (int j = 0; j < 12; ++j) {
                int d = lane + 64 * j;
                float c1v = c1buf[k][d];
                float v = cc ? c1v : (tsum[d] - c1v);
                vals[j] = v;
                ss = fmaf(v, v, ss);
            }
            ss = waveReduceSum(ss);
            float iv = 1.0f / fmaxf(sqrtf(ss), 1e-12f);
#pragma unroll
            for (int j = 0; j < 12; ++j)
                cent[wave][lane + 64 * j] = vals[j] * iv;
        }
        __syncthreads();
    }

    // ---- scatter: vc[idx,0,0] += centroids_final[b,k,0,0] (c0 row, element 0)
    if (t < KC) {
        atomicAdd(delta + sidx[t], cent[2 * t][0]);
    }
}

__global__ __launch_bounds__(256) void vcnorm_kernel(
    const float* __restrict__ vc,
    const float* __restrict__ delta,
    float* __restrict__ out)          // (V, 2, D)
{
    const int t = threadIdx.x;
    const int lane = t & 63;
    const int wave = t >> 6;
    const int r = blockIdx.x * 4 + wave;      // row in [0, 2V)
    if (r >= 2 * VV) return;
    const int v = r >> 1;
    const int c = r & 1;
    const float* src = vc + (size_t)r * DD;
    float4 x[3];
#pragma unroll
    for (int j = 0; j < 3; ++j)
        x[j] = *(const float4*)(src + (lane + 64 * j) * 4);
    if (c == 0 && lane == 0) x[0].x += delta[v];
    float ss = 0.f;
#pragma unroll
    for (int j = 0; j < 3; ++j)
        ss += x[j].x * x[j].x + x[j].y * x[j].y + x[j].z * x[j].z + x[j].w * x[j].w;
    ss = waveReduceSum(ss);
    float iv = 1.0f / fmaxf(sqrtf(ss), 1e-12f);
    float* dst = out + (size_t)r * DD;
#pragma unroll
    for (int j = 0; j < 3; ++j) {
        float4 y = make_float4(x[j].x * iv, x[j].y * iv, x[j].z * iv, x[j].w * iv);
        *(float4*)(dst + (lane + 64 * j) * 4) = y;
    }
}

extern "C" void kernel_launch(void* const* d_in, const int* in_sizes, int n_in,
                              void* d_out, int out_size, void* d_ws, size_t ws_size,
                              hipStream_t stream) {
    const float* tokens = (const float*)d_in[0];
    const float* vc     = (const float*)d_in[1];
    const int*   topk   = (const int*)d_in[2];
    float* out          = (float*)d_out;
    float* assignments  = out;                                   // B*NT*KC floats
    float* vcnew        = out + (size_t)BB * NT * KC;            // V*2*D floats
    float* delta        = (float*)d_ws;                          // V floats

    hipMemsetAsync(delta, 0, VV * sizeof(float), stream);
    hipLaunchKernelGGL(kmeans_kernel, dim3(BB), dim3(1024), 0, stream,
                       tokens, vc, topk, assignments, delta);
    hipLaunchKernelGGL(vcnorm_kernel, dim3((2 * VV + 3) / 4), dim3(256), 0, stream,
                       vc, delta, vcnew);
}